// Round 1
// baseline (611.387 us; speedup 1.0000x reference)
//
#include <hip/hip_runtime.h>
#include <hip/hip_bf16.h>

typedef __hip_bfloat16 bf16;
typedef __attribute__((ext_vector_type(8))) short bf16x8;
typedef __attribute__((ext_vector_type(4))) float f32x4;

#define H 128
#define F3H 384
#define E_RBF 20
#define NLAYER 3

__device__ __forceinline__ float silu_f(float x) { return x / (1.0f + __expf(-x)); }
__device__ __forceinline__ float b2f(bf16 x) { return __bfloat162float(x); }
__device__ __forceinline__ float u2f(unsigned short u) { return __uint_as_float((unsigned)u << 16); }

constexpr float PI_F = 3.14159265358979323846f;
constexpr float CUT = 5.0f;

// ---------------- CSR build ----------------
__global__ __launch_bounds__(256) void csr_hist(
    const int* __restrict__ edge, int* __restrict__ cnt, int nE) {
  int e = blockIdx.x * blockDim.x + threadIdx.x;
  if (e < nE) atomicAdd(&cnt[edge[2 * e]], 1);
}

__global__ __launch_bounds__(256) void csr_scan(
    const int* __restrict__ cnt, int* __restrict__ rowstart, int* __restrict__ cur, int N) {
  __shared__ int part[256];
  int t = threadIdx.x;
  int chunk = (N + 255) / 256;
  int lo = t * chunk; if (lo > N) lo = N;
  int hi = lo + chunk; if (hi > N) hi = N;
  int s = 0;
  for (int i = lo; i < hi; i++) s += cnt[i];
  part[t] = s;
  __syncthreads();
  if (t == 0) {
    int r = 0;
    for (int i = 0; i < 256; i++) { int v = part[i]; part[i] = r; r += v; }
  }
  __syncthreads();
  int r = part[t];
  for (int i = lo; i < hi; i++) { rowstart[i] = r; cur[i] = r; r += cnt[i]; }
}

__global__ __launch_bounds__(256) void csr_fill(
    const int* __restrict__ edge, int* __restrict__ cur, int* __restrict__ elist, int nE) {
  int e = blockIdx.x * blockDim.x + threadIdx.x;
  if (e < nE) {
    int d = edge[2 * e];
    int p = atomicAdd(&cur[d], 1);
    elist[p] = e;
  }
}

// ---------------- edge geometry pack ----------------
__global__ __launch_bounds__(256) void edge_pack(
    const int* __restrict__ elist, const int* __restrict__ edge,
    const float* __restrict__ edist, const float* __restrict__ ediff,
    int* __restrict__ srcs, float* __restrict__ geo, int nE) {
  int j = blockIdx.x * blockDim.x + threadIdx.x;
  if (j >= nE) return;
  int e = elist[j];
  srcs[j] = edge[2 * e + 1];
  float d = edist[e];
  float inv = 1.0f / d;
  float th = d * (PI_F / CUT);
  float s1 = sinf(th), c1 = cosf(th);
  float fc = (d < CUT) ? 0.5f * (c1 + 1.0f) : 0.0f;
  float* g = geo + (size_t)j * 24;
  float twoc = 2.0f * c1;
  float skp = 0.0f, sk = s1;
  #pragma unroll
  for (int k = 0; k < E_RBF; k++) {
    g[k] = sk * inv * fc;
    float nx = twoc * sk - skp;
    skp = sk; sk = nx;
  }
  g[20] = ediff[3 * (size_t)e] * inv;
  g[21] = ediff[3 * (size_t)e + 1] * inv;
  g[22] = ediff[3 * (size_t)e + 2] * inv;
  g[23] = fc;
}

// ---------------- node init (fp32 + bf16 shadow) ----------------
__global__ __launch_bounds__(H) void node_init(
    const int* __restrict__ z, const float* __restrict__ embed,
    float* __restrict__ ns, bf16* __restrict__ ns16, int N) {
  int i = blockIdx.x;
  int h = threadIdx.x;
  float v = embed[(size_t)z[i] * H + h];
  ns[(size_t)i * H + h] = v;
  ns16[(size_t)i * H + h] = __float2bfloat16(v);
}

// ---------------- pack U/V weights into MFMA B-fragment layout ----------------
__global__ __launch_bounds__(256) void pack_w(
    const float* __restrict__ Wu, const float* __restrict__ Wv,
    bf16* __restrict__ wp) {
  int t = blockIdx.x * blockDim.x + threadIdx.x;   // 12288 total
  if (t >= 3 * 2 * 4 * 8 * 64) return;
  int lane = t & 63;
  int c    = (t >> 6) & 7;
  int kb   = (t >> 9) & 3;
  int mat  = (t >> 11) & 1;
  int l    = t >> 12;
  const float* src = (mat ? Wv : Wu) + (size_t)l * H * H;
  bf16* dst = wp + ((size_t)(l * 2 + mat) * 16384) + (((kb * 8 + c) * 64 + lane) * 8);
  int quad = lane >> 4;
  int n = c * 16 + (lane & 15);
  #pragma unroll
  for (int j = 0; j < 8; j++) {
    int k = kb * 32 + quad * 8 + j;
    dst[j] = __float2bfloat16(src[(size_t)k * H + n]);
  }
}

// ---------------- generic B-fragment packer ----------------
__global__ __launch_bounds__(256) void pack_b(
    const float* __restrict__ src, bf16* __restrict__ dst,
    int K, int ncols, int L) {
  int kblocks = K >> 5, ncols16 = ncols >> 4;
  int total = L * kblocks * ncols16 * 64;
  int t = blockIdx.x * blockDim.x + threadIdx.x;
  if (t >= total) return;
  int lane = t & 63;
  int idx = t >> 6;
  int c = idx % ncols16; idx /= ncols16;
  int kb = idx % kblocks; idx /= kblocks;
  int l = idx;
  const float* s = src + (size_t)l * K * ncols;
  bf16* d = dst + (size_t)l * K * ncols + (((kb * ncols16 + c) * 64 + lane) * 8);
  int quad = lane >> 4;
  int n = c * 16 + (lane & 15);
  #pragma unroll
  for (int j = 0; j < 8; j++) {
    int k = kb * 32 + quad * 8 + j;
    d[j] = __float2bfloat16(s[(size_t)k * ncols + n]);
  }
}

// ---------------- MFMA dual GEMM: Uv/Vv ----------------
__global__ __launch_bounds__(256) void gemm_uv_mfma(
    const bf16* __restrict__ A, const bf16* __restrict__ Wp,
    const float* __restrict__ bu, const float* __restrict__ bv,
    float* __restrict__ Cu, float* __restrict__ Cv, int M) {
  int wave = threadIdx.x >> 6;
  int lane = threadIdx.x & 63;
  int r0 = blockIdx.x * 64 + wave * 16;
  int quad = lane >> 4;
  int nn = lane & 15;
  int arow = r0 + nn;
  if (arow >= M) arow = M - 1;
  f32x4 accu[8] = {};
  f32x4 accv[8] = {};
  for (int kb = 0; kb < 4; kb++) {
    bf16x8 af = *(const bf16x8*)&A[(size_t)arow * H + kb * 32 + quad * 8];
    #pragma unroll
    for (int c = 0; c < 8; c++) {
      bf16x8 bfu = *(const bf16x8*)&Wp[(((kb * 8 + c) * 64) + lane) * 8];
      bf16x8 bfv = *(const bf16x8*)&Wp[16384 + (((kb * 8 + c) * 64) + lane) * 8];
      accu[c] = __builtin_amdgcn_mfma_f32_16x16x32_bf16(af, bfu, accu[c], 0, 0, 0);
      accv[c] = __builtin_amdgcn_mfma_f32_16x16x32_bf16(af, bfv, accv[c], 0, 0, 0);
    }
  }
  #pragma unroll
  for (int c = 0; c < 8; c++) {
    int n = c * 16 + nn;
    float bub = bu[n], bvb = bv[n];
    #pragma unroll
    for (int r = 0; r < 4; r++) {
      int row = r0 + quad * 4 + r;
      if (row < M) {
        Cu[(size_t)row * H + n] = accu[c][r] + bub;
        Cv[(size_t)row * H + n] = accv[c][r] + bvb;
      }
    }
  }
}

// ---------------- vnorm -> A2[:,0:128] bf16 ----------------
__global__ __launch_bounds__(256) void vnorm_a2(
    const float* __restrict__ Vv, bf16* __restrict__ A2, int N) {
  int t = blockIdx.x * blockDim.x + threadIdx.x;
  if (t >= N * H) return;
  int i = t >> 7, h = t & 127;
  float v0 = Vv[(size_t)(3 * i + 0) * H + h];
  float v1 = Vv[(size_t)(3 * i + 1) * H + h];
  float v2 = Vv[(size_t)(3 * i + 2) * H + h];
  A2[(size_t)i * 256 + h] = __float2bfloat16(sqrtf(v0 * v0 + v1 * v1 + v2 * v2));
}

// ---------------- generic MFMA stage-1: out = silu(A@W+b) -> bf16, 128 cols ----------------
template<int KB>
__global__ __launch_bounds__(256) void gemm_silu_mfma(
    const bf16* __restrict__ A, const bf16* __restrict__ Wp,
    const float* __restrict__ bias, bf16* __restrict__ out, int M) {
  int wave = threadIdx.x >> 6, lane = threadIdx.x & 63;
  int rowg = wave >> 1, ch = wave & 1;
  int r0 = blockIdx.x * 32 + rowg * 16;
  int quad = lane >> 4, nn = lane & 15;
  int arow = r0 + nn; if (arow >= M) arow = M - 1;
  f32x4 acc[4] = {};
  for (int kb = 0; kb < KB; kb++) {
    bf16x8 af = *(const bf16x8*)&A[(size_t)arow * (KB * 32) + kb * 32 + quad * 8];
    #pragma unroll
    for (int c = 0; c < 4; c++) {
      int cg = ch * 4 + c;
      bf16x8 bw = *(const bf16x8*)&Wp[(((kb * 8 + cg) * 64) + lane) * 8];
      acc[c] = __builtin_amdgcn_mfma_f32_16x16x32_bf16(af, bw, acc[c], 0, 0, 0);
    }
  }
  #pragma unroll
  for (int c = 0; c < 4; c++) {
    int n = (ch * 4 + c) * 16 + nn;
    float bb = bias[n];
    #pragma unroll
    for (int r = 0; r < 4; r++) {
      int row = r0 + quad * 4 + r;
      if (row < M) out[(size_t)row * H + n] = __float2bfloat16(silu_f(acc[c][r] + bb));
    }
  }
}

// ---------------- MFMA stage-2, 384 cols -> bf16 gather layout [i][h][4] ----------------
__global__ __launch_bounds__(256) void gemm_so_mfma(
    const bf16* __restrict__ m1, const bf16* __restrict__ Wp,
    const float* __restrict__ b2, bf16* __restrict__ so, int M) {
  int wave = threadIdx.x >> 6, lane = threadIdx.x & 63;
  int rowg = wave >> 1, ch = wave & 1;
  int r0 = blockIdx.x * 32 + rowg * 16;
  int quad = lane >> 4, nn = lane & 15;
  int arow = r0 + nn; if (arow >= M) arow = M - 1;
  f32x4 a0[4] = {}, a1[4] = {}, a2[4] = {};
  for (int kb = 0; kb < 4; kb++) {
    bf16x8 af = *(const bf16x8*)&m1[(size_t)arow * H + kb * 32 + quad * 8];
    #pragma unroll
    for (int c = 0; c < 4; c++) {
      int cg = ch * 4 + c;
      bf16x8 b0 = *(const bf16x8*)&Wp[(((kb * 24 + cg) * 64) + lane) * 8];
      bf16x8 b1v = *(const bf16x8*)&Wp[(((kb * 24 + cg + 8) * 64) + lane) * 8];
      bf16x8 b2v = *(const bf16x8*)&Wp[(((kb * 24 + cg + 16) * 64) + lane) * 8];
      a0[c] = __builtin_amdgcn_mfma_f32_16x16x32_bf16(af, b0, a0[c], 0, 0, 0);
      a1[c] = __builtin_amdgcn_mfma_f32_16x16x32_bf16(af, b1v, a1[c], 0, 0, 0);
      a2[c] = __builtin_amdgcn_mfma_f32_16x16x32_bf16(af, b2v, a2[c], 0, 0, 0);
    }
  }
  #pragma unroll
  for (int c = 0; c < 4; c++) {
    int n = (ch * 4 + c) * 16 + nn;
    float bb0 = b2[n], bb1 = b2[H + n], bb2 = b2[2 * H + n];
    #pragma unroll
    for (int r = 0; r < 4; r++) {
      int row = r0 + quad * 4 + r;
      if (row < M) {
        bf16* sp = so + ((size_t)row * H + n) * 4;
        sp[0] = __float2bfloat16(a0[c][r] + bb0);
        sp[1] = __float2bfloat16(a1[c][r] + bb1);
        sp[2] = __float2bfloat16(a2[c][r] + bb2);
      }
    }
  }
}

// ---------------- MFMA stage-2, 128 cols -> fp32 (readout) ----------------
__global__ __launch_bounds__(256) void gemm_ro2_mfma(
    const bf16* __restrict__ m1, const bf16* __restrict__ Wp,
    const float* __restrict__ b2, float* __restrict__ out, int M) {
  int wave = threadIdx.x >> 6, lane = threadIdx.x & 63;
  int rowg = wave >> 1, ch = wave & 1;
  int r0 = blockIdx.x * 32 + rowg * 16;
  int quad = lane >> 4, nn = lane & 15;
  int arow = r0 + nn; if (arow >= M) arow = M - 1;
  f32x4 acc[4] = {};
  for (int kb = 0; kb < 4; kb++) {
    bf16x8 af = *(const bf16x8*)&m1[(size_t)arow * H + kb * 32 + quad * 8];
    #pragma unroll
    for (int c = 0; c < 4; c++) {
      int cg = ch * 4 + c;
      bf16x8 bw = *(const bf16x8*)&Wp[(((kb * 8 + cg) * 64) + lane) * 8];
      acc[c] = __builtin_amdgcn_mfma_f32_16x16x32_bf16(af, bw, acc[c], 0, 0, 0);
    }
  }
  #pragma unroll
  for (int c = 0; c < 4; c++) {
    int n = (ch * 4 + c) * 16 + nn;
    float bb = b2[n];
    #pragma unroll
    for (int r = 0; r < 4; r++) {
      int row = r0 + quad * 4 + r;
      if (row < M) out[(size_t)row * H + n] = acc[c][r] + bb;
    }
  }
}

// ---------------- MFMA update-MLP stage 2 + gating epilogue (+ns16) ----------------
__global__ __launch_bounds__(256) void gemm_mo_ep(
    const bf16* __restrict__ m1, const bf16* __restrict__ Wp,
    const float* __restrict__ b2,
    float* __restrict__ ns, bf16* __restrict__ ns16,
    float* __restrict__ nv, bf16* __restrict__ nvb16,
    const float* __restrict__ Uv, const float* __restrict__ Vv, int M) {
  int wave = threadIdx.x >> 6, lane = threadIdx.x & 63;
  int rowg = wave >> 1, ch = wave & 1;
  int r0 = blockIdx.x * 32 + rowg * 16;
  int quad = lane >> 4, nn = lane & 15;
  int arow = r0 + nn; if (arow >= M) arow = M - 1;
  f32x4 aav[4] = {}, aas[4] = {}, asz[4] = {};
  for (int kb = 0; kb < 4; kb++) {
    bf16x8 af = *(const bf16x8*)&m1[(size_t)arow * H + kb * 32 + quad * 8];
    #pragma unroll
    for (int c = 0; c < 4; c++) {
      int cg = ch * 4 + c;
      bf16x8 b0 = *(const bf16x8*)&Wp[(((kb * 24 + cg) * 64) + lane) * 8];
      bf16x8 b1v = *(const bf16x8*)&Wp[(((kb * 24 + cg + 8) * 64) + lane) * 8];
      bf16x8 b2v = *(const bf16x8*)&Wp[(((kb * 24 + cg + 16) * 64) + lane) * 8];
      aav[c] = __builtin_amdgcn_mfma_f32_16x16x32_bf16(af, b0, aav[c], 0, 0, 0);
      aas[c] = __builtin_amdgcn_mfma_f32_16x16x32_bf16(af, b1v, aas[c], 0, 0, 0);
      asz[c] = __builtin_amdgcn_mfma_f32_16x16x32_bf16(af, b2v, asz[c], 0, 0, 0);
    }
  }
  #pragma unroll
  for (int c = 0; c < 4; c++) {
    int n = (ch * 4 + c) * 16 + nn;
    float bav = b2[n], bas = b2[H + n], bss = b2[2 * H + n];
    #pragma unroll
    for (int r = 0; r < 4; r++) {
      int row = r0 + quad * 4 + r;
      if (row < M) {
        float avv = aav[c][r] + bav;
        float asv = aas[c][r] + bas;
        float ass = asz[c][r] + bss;
        float u0 = Uv[(size_t)(3 * row + 0) * H + n];
        float u1 = Uv[(size_t)(3 * row + 1) * H + n];
        float u2 = Uv[(size_t)(3 * row + 2) * H + n];
        float v0 = Vv[(size_t)(3 * row + 0) * H + n];
        float v1 = Vv[(size_t)(3 * row + 1) * H + n];
        float v2 = Vv[(size_t)(3 * row + 2) * H + n];
        float dot = u0 * v0 + u1 * v1 + u2 * v2;
        float ns_new = ns[(size_t)row * H + n] + asv * dot + ass;
        ns[(size_t)row * H + n] = ns_new;
        ns16[(size_t)row * H + n] = __float2bfloat16(ns_new);
        float n0 = nv[(size_t)(3 * row + 0) * H + n] + avv * u0;
        float n1 = nv[(size_t)(3 * row + 1) * H + n] + avv * u1;
        float n2 = nv[(size_t)(3 * row + 2) * H + n] + avv * u2;
        nv[(size_t)(3 * row + 0) * H + n] = n0;
        nv[(size_t)(3 * row + 1) * H + n] = n1;
        nv[(size_t)(3 * row + 2) * H + n] = n2;
        bf16* nq = nvb16 + ((size_t)row * H + n) * 4;
        nq[0] = __float2bfloat16(n0);
        nq[1] = __float2bfloat16(n1);
        nq[2] = __float2bfloat16(n2);
      }
    }
  }
}

// ---------------- message: pinned-register filter weights, fused 8B gathers ----------------
// so/nvb16 gather layout: [i][h][4] bf16 (c = 0..2, pad) -> one dwordx2 per gather.
// wf pinned via asm to defeat rematerialization (old version: VGPR=48 -> Wf reloaded per edge).
template<bool HASNV>
__global__ __launch_bounds__(128, 3) void message3(
    const int* __restrict__ srcs, const int* __restrict__ rowstart,
    const int* __restrict__ cnt, const float* __restrict__ geo,
    const float* __restrict__ Wf, const float* __restrict__ bfb,
    const bf16* __restrict__ sop, const bf16* __restrict__ nvgp,
    const float* __restrict__ nvA,
    float* __restrict__ ns, float* __restrict__ nvB,
    bf16* __restrict__ nvmsg16, bf16* __restrict__ A2, int N) {
  int h = threadIdx.x;

  float wf0[E_RBF], wf1[E_RBF], wf2[E_RBF];
  #pragma unroll
  for (int k = 0; k < E_RBF; k++) {
    wf0[k] = Wf[k * F3H + h];
    wf1[k] = Wf[k * F3H + H + h];
    wf2[k] = Wf[k * F3H + 2 * H + h];
  }
  // Force materialization in VGPRs: compiler may otherwise rematerialize
  // these loads inside the edge loop (observed: VGPR_Count=48 < 60 weights).
  #pragma unroll
  for (int k = 0; k < E_RBF; k++)
    asm volatile("" : "+v"(wf0[k]), "+v"(wf1[k]), "+v"(wf2[k]));
  float bb0 = bfb[h], bb1 = bfb[H + h], bb2 = bfb[2 * H + h];

  for (int i = blockIdx.x; i < N; i += gridDim.x) {
    float accs = 0.0f, a0 = 0.0f, a1 = 0.0f, a2 = 0.0f;
    int jlo = rowstart[i], jhi = jlo + cnt[i];
    int src_n = 0;
    if (jlo < jhi) src_n = srcs[jlo];
    for (int j = jlo; j < jhi; j++) {
      int src = src_n;
      int jn = (j + 1 < jhi) ? (j + 1) : j;
      src_n = srcs[jn];
      // issue gathers early (src was prefetched last iteration)
      const ushort4 sv = *(const ushort4*)&sop[((size_t)src * H + h) * 4];
      ushort4 nvv = make_ushort4(0, 0, 0, 0);
      if (HASNV) nvv = *(const ushort4*)&nvgp[((size_t)src * H + h) * 4];
      const float4* gp = (const float4*)(geo + (size_t)j * 24);
      float4 g0 = gp[0], g1 = gp[1], g2 = gp[2], g3 = gp[3], g4 = gp[4], g5 = gp[5];
      float fc = g5.w;
      float f0 = bb0 * fc, f1 = bb1 * fc, f2 = bb2 * fc;
      float gg[E_RBF] = {g0.x, g0.y, g0.z, g0.w, g1.x, g1.y, g1.z, g1.w,
                         g2.x, g2.y, g2.z, g2.w, g3.x, g3.y, g3.z, g3.w,
                         g4.x, g4.y, g4.z, g4.w};
      #pragma unroll
      for (int k = 0; k < E_RBF; k++) {
        f0 += gg[k] * wf0[k];
        f1 += gg[k] * wf1[k];
        f2 += gg[k] * wf2[k];
      }
      float u0 = g5.x, u1 = g5.y, u2 = g5.z;
      float gsv = f0 * u2f(sv.x);
      float gev = f1 * u2f(sv.y);
      accs += f2 * u2f(sv.z);
      if (HASNV) {
        a0 += u2f(nvv.x) * gsv + gev * u0;
        a1 += u2f(nvv.y) * gsv + gev * u1;
        a2 += u2f(nvv.z) * gsv + gev * u2;
      } else {
        a0 += gev * u0;
        a1 += gev * u1;
        a2 += gev * u2;
      }
    }

    float ns_new = ns[(size_t)i * H + h] + accs;
    ns[(size_t)i * H + h] = ns_new;
    A2[(size_t)i * 256 + 128 + h] = __float2bfloat16(ns_new);
    float o0, o1, o2;
    if (HASNV) {
      const float* nvi = nvA + (size_t)i * F3H;
      o0 = nvi[h] + a0;
      o1 = nvi[H + h] + a1;
      o2 = nvi[2 * H + h] + a2;
    } else {
      o0 = a0; o1 = a1; o2 = a2;
    }
    nvB[(size_t)i * F3H + h]         = o0;
    nvB[(size_t)i * F3H + H + h]     = o1;
    nvB[(size_t)i * F3H + 2 * H + h] = o2;
    nvmsg16[(size_t)i * F3H + h]         = __float2bfloat16(o0);
    nvmsg16[(size_t)i * F3H + H + h]     = __float2bfloat16(o1);
    nvmsg16[(size_t)i * F3H + 2 * H + h] = __float2bfloat16(o2);
  }
}

extern "C" void kernel_launch(void* const* d_in, const int* in_sizes, int n_in,
                              void* d_out, int out_size, void* d_ws, size_t ws_size,
                              hipStream_t stream) {
  const int*   z     = (const int*)d_in[0];
  const int*   edge  = (const int*)d_in[1];
  const float* ediff = (const float*)d_in[2];
  const float* edist = (const float*)d_in[3];
  const float* embed = (const float*)d_in[4];
  const float* mfw   = (const float*)d_in[5];
  const float* mfb   = (const float*)d_in[6];
  const float* mw1   = (const float*)d_in[7];
  const float* mb1   = (const float*)d_in[8];
  const float* mw2   = (const float*)d_in[9];
  const float* mb2   = (const float*)d_in[10];
  const float* uUw   = (const float*)d_in[11];
  const float* uUb   = (const float*)d_in[12];
  const float* uVw   = (const float*)d_in[13];
  const float* uVb   = (const float*)d_in[14];
  const float* uw1   = (const float*)d_in[15];
  const float* ub1   = (const float*)d_in[16];
  const float* uw2   = (const float*)d_in[17];
  const float* ub2   = (const float*)d_in[18];
  const float* rw1   = (const float*)d_in[19];
  const float* rb1   = (const float*)d_in[20];
  const float* rw2   = (const float*)d_in[21];
  const float* rb2   = (const float*)d_in[22];

  const int N  = in_sizes[0];   // 10000
  const int nE = in_sizes[3];   // 160000

  float* ws = (float*)d_ws;
  size_t off = 0;
  float* ns      = ws + off; off += (size_t)N * H;
  float* nvA     = ws + off; off += (size_t)N * F3H;
  float* nvB     = ws + off; off += (size_t)N * F3H;
  float* Vv      = ws + off; off += (size_t)N * F3H;
  float* geo     = ws + off; off += (size_t)nE * 24;
  bf16* so       = (bf16*)(ws + off); off += (size_t)N * 256;       // N*128*4 bf16
  bf16* nvb16    = (bf16*)(ws + off); off += (size_t)N * 256;       // N*128*4 bf16
  bf16* nvmsg16  = (bf16*)(ws + off); off += (size_t)N * F3H / 2;
  bf16* A2       = (bf16*)(ws + off); off += (size_t)N * 128;       // N*256 bf16
  bf16* m1buf    = (bf16*)(ws + off); off += (size_t)N * 64;        // N*128 bf16
  bf16* ns16     = (bf16*)(ws + off); off += (size_t)N * 64;        // N*128 bf16
  bf16* wpack    = (bf16*)(ws + off); off += 3 * 2 * 16384 / 2;     // UV
  bf16* wp_m1    = (bf16*)(ws + off); off += 3 * 256 * 128 / 2;
  bf16* wp_m2    = (bf16*)(ws + off); off += 3 * 128 * 384 / 2;
  bf16* wp_sm1   = (bf16*)(ws + off); off += 3 * 128 * 128 / 2;
  bf16* wp_sm2   = (bf16*)(ws + off); off += 3 * 128 * 384 / 2;
  bf16* wp_ro1   = (bf16*)(ws + off); off += 128 * 128 / 2;
  bf16* wp_ro2   = (bf16*)(ws + off); off += 128 * 128 / 2;
  int* srcs     = (int*)(ws + off); off += nE;
  int* cnt      = (int*)(ws + off); off += N;
  int* rowstart = (int*)(ws + off); off += N;
  int* cur      = (int*)(ws + off); off += N;
  int* elist    = (int*)(ws + off); off += nE;

  const int tilesN = (N + 31) / 32;            // 313
  const int uvBlks = (3 * N + 63) / 64;        // 469
  const int msgGrid = 2048;                    // grid-stride: ~5 nodes/block

  (void)hipMemsetAsync(cnt, 0, (size_t)N * sizeof(int), stream);
  csr_hist<<<(nE + 255) / 256, 256, 0, stream>>>(edge, cnt, nE);
  csr_scan<<<1, 256, 0, stream>>>(cnt, rowstart, cur, N);
  csr_fill<<<(nE + 255) / 256, 256, 0, stream>>>(edge, cur, elist, nE);
  edge_pack<<<(nE + 255) / 256, 256, 0, stream>>>(elist, edge, edist, ediff, srcs, geo, nE);
  pack_w<<<48, 256, 0, stream>>>(uUw, uVw, wpack);
  pack_b<<<48, 256, 0, stream>>>(uw1, wp_m1, 256, 128, 3);
  pack_b<<<72, 256, 0, stream>>>(uw2, wp_m2, 128, 384, 3);
  pack_b<<<24, 256, 0, stream>>>(mw1, wp_sm1, 128, 128, 3);
  pack_b<<<72, 256, 0, stream>>>(mw2, wp_sm2, 128, 384, 3);
  pack_b<<<8, 256, 0, stream>>>(rw1, wp_ro1, 128, 128, 1);
  pack_b<<<8, 256, 0, stream>>>(rw2, wp_ro2, 128, 128, 1);

  node_init<<<N, H, 0, stream>>>(z, embed, ns, ns16, N);

  float* nv_cur = nvA;
  float* nv_nxt = nvB;
  for (int l = 0; l < NLAYER; l++) {
    // scalar message MLP (MFMA): m1 = silu(ns16@mw1+mb1); so = m1@mw2+mb2
    gemm_silu_mfma<4><<<tilesN, 256, 0, stream>>>(
        ns16, wp_sm1 + (size_t)l * 128 * 128, mb1 + (size_t)l * H, m1buf, N);
    gemm_so_mfma<<<tilesN, 256, 0, stream>>>(
        m1buf, wp_sm2 + (size_t)l * 128 * 384, mb2 + (size_t)l * F3H, so, N);

    if (l == 0)
      message3<false><<<msgGrid, 128, 0, stream>>>(srcs, rowstart, cnt, geo,
                                           mfw + (size_t)l * E_RBF * F3H, mfb + (size_t)l * F3H,
                                           so, nvb16, nv_cur, ns, nv_nxt, nvmsg16, A2, N);
    else
      message3<true><<<msgGrid, 128, 0, stream>>>(srcs, rowstart, cnt, geo,
                                          mfw + (size_t)l * E_RBF * F3H, mfb + (size_t)l * F3H,
                                          so, nvb16, nv_cur, ns, nv_nxt, nvmsg16, A2, N);

    float* Uv = nv_cur;  // dead after message3 — reuse as Uv scratch
    gemm_uv_mfma<<<uvBlks, 256, 0, stream>>>(
        nvmsg16, wpack + (size_t)l * 2 * 16384,
        uUb + (size_t)l * H, uVb + (size_t)l * H,
        Uv, Vv, 3 * N);

    vnorm_a2<<<(N * H + 255) / 256, 256, 0, stream>>>(Vv, A2, N);
    gemm_silu_mfma<8><<<tilesN, 256, 0, stream>>>(
        A2, wp_m1 + (size_t)l * 256 * 128, ub1 + (size_t)l * H, m1buf, N);
    gemm_mo_ep<<<tilesN, 256, 0, stream>>>(
        m1buf, wp_m2 + (size_t)l * 128 * 384, ub2 + (size_t)l * F3H,
        ns, ns16, nv_nxt, nvb16, Uv, Vv, N);

    float* t = nv_cur; nv_cur = nv_nxt; nv_nxt = t;
  }

  gemm_silu_mfma<4><<<tilesN, 256, 0, stream>>>(ns16, wp_ro1, rb1, m1buf, N);
  gemm_ro2_mfma<<<tilesN, 256, 0, stream>>>(m1buf, wp_ro2, rb2, (float*)d_out, N);
}